// Round 1
// baseline (4807.576 us; speedup 1.0000x reference)
//
#include <hip/hip_runtime.h>
#include <stdint.h>

namespace {
constexpr int kB = 64, kS = 512, kD = 768, kH = 3, kDK = 64;
constexpr int kTAG = 33, kNB = 8, kSTART = 31, kSTOP = 32;
constexpr float kNEG = -1e30f;
constexpr size_t kHead = (size_t)kB * kH * kS * kDK;      // 6,291,456 floats per Q/K/V/OA buffer
constexpr size_t kQOFF = 0, kKOFF = kHead, kVOFF = 2 * kHead, kOAOFF = 3 * kHead;
constexpr size_t kWsNeed = 4 * kHead * sizeof(float);     // ~100.7 MB
constexpr size_t kBpsByte = (size_t)kB * kS * kTAG * 4;   // BPS (u16) byte offset inside dead Q region
}

// ---------------- K1: QKV projection, f32 SIMT GEMM (BM=128,BN=64,BK=16) ----
__global__ __launch_bounds__(256) void k_qkv(
    const float* __restrict__ X, const float* __restrict__ wq,
    const float* __restrict__ wk, const float* __restrict__ wv,
    float* __restrict__ ws)
{
  __shared__ float As[16][132];
  __shared__ float Bs[16][68];
  const int bx = blockIdx.x;            // 0..8 -> (type, head)
  const int m0 = blockIdx.y * 128;
  const int tid = threadIdx.x;
  const int tx = tid & 15, ty = tid >> 4;
  const int typ = bx / 3, h = bx % 3;
  const float* wptr = (typ == 0) ? wq : (typ == 1) ? wk : wv;
  float* outp = ws + ((typ == 0) ? kQOFF : (typ == 1) ? kKOFF : kVOFF);

  float acc[8][4] = {};
  const int rowA = tid >> 2, ka = (tid & 3) * 4;
  const int rowB = tid >> 6, cb = tid & 63;
  for (int k0 = 0; k0 < kD; k0 += 16) {
    #pragma unroll
    for (int half = 0; half < 2; ++half) {
      const int r = rowA + half * 64;
      const float4 v = *(const float4*)(X + (size_t)(m0 + r) * kD + k0 + ka);
      As[ka + 0][r] = v.x; As[ka + 1][r] = v.y; As[ka + 2][r] = v.z; As[ka + 3][r] = v.w;
    }
    #pragma unroll
    for (int q = 0; q < 4; ++q) {
      const int k = rowB + q * 4;
      Bs[k][cb] = wptr[((size_t)h * kD + k0 + k) * 64 + cb];
    }
    __syncthreads();
    #pragma unroll
    for (int kk = 0; kk < 16; ++kk) {
      const float4 a0 = *(const float4*)&As[kk][ty * 8];
      const float4 a1 = *(const float4*)&As[kk][ty * 8 + 4];
      const float4 b0 = *(const float4*)&Bs[kk][tx * 4];
      const float a[8] = {a0.x, a0.y, a0.z, a0.w, a1.x, a1.y, a1.z, a1.w};
      const float bv[4] = {b0.x, b0.y, b0.z, b0.w};
      #pragma unroll
      for (int i = 0; i < 8; ++i)
        #pragma unroll
        for (int j = 0; j < 4; ++j) acc[i][j] += a[i] * bv[j];
    }
    __syncthreads();
  }
  #pragma unroll
  for (int i = 0; i < 8; ++i) {
    const int m = m0 + ty * 8 + i;
    const int b = m >> 9, s = m & 511;
    *(float4*)(outp + ((size_t)(b * kH + h) * kS + s) * kDK + tx * 4) =
        make_float4(acc[i][0], acc[i][1], acc[i][2], acc[i][3]);
  }
}

// ---------------- K2: flash-style attention, 64 q-rows per block ------------
__global__ __launch_bounds__(256) void k_attn(
    const float* __restrict__ Q, const float* __restrict__ K,
    const float* __restrict__ V, float* __restrict__ oa)
{
  __shared__ float Qt[64][68];
  __shared__ float Kt[64][68];
  __shared__ float Vl[64][68];
  __shared__ float Pl[64][68];
  const int qt = blockIdx.x, h = blockIdx.y, b = blockIdx.z;
  const int tid = threadIdx.x;
  const int tx = tid & 15, ty = tid >> 4;
  const int r0 = ty * 4, c0 = tx * 4;
  const size_t base = (size_t)(b * kH + h) * kS * kDK;

  {
    const int row = tid >> 2, cc = (tid & 3) * 4;
    const float* src = Q + base + (size_t)(qt * 64 + row) * kDK;
    #pragma unroll
    for (int q = 0; q < 4; ++q) {
      const int c = cc + q * 16;
      const float4 v = *(const float4*)(src + c);
      Qt[c + 0][row] = v.x; Qt[c + 1][row] = v.y; Qt[c + 2][row] = v.z; Qt[c + 3][row] = v.w;
    }
  }
  float m_r[4], l_r[4], O[4][4];
  #pragma unroll
  for (int i = 0; i < 4; ++i) {
    m_r[i] = -__builtin_huge_valf(); l_r[i] = 0.f;
    #pragma unroll
    for (int j = 0; j < 4; ++j) O[i][j] = 0.f;
  }
  for (int kt = 0; kt < 8; ++kt) {
    __syncthreads();
    {
      const int row = tid >> 2, cc = (tid & 3) * 4;
      const float* srck = K + base + (size_t)(kt * 64 + row) * kDK;
      const float* srcv = V + base + (size_t)(kt * 64 + row) * kDK;
      #pragma unroll
      for (int q = 0; q < 4; ++q) {
        const int c = cc + q * 16;
        const float4 v = *(const float4*)(srck + c);
        Kt[c + 0][row] = v.x; Kt[c + 1][row] = v.y; Kt[c + 2][row] = v.z; Kt[c + 3][row] = v.w;
        *(float4*)&Vl[row][c] = *(const float4*)(srcv + c);
      }
    }
    __syncthreads();
    float sc[4][4] = {};
    for (int k = 0; k < 64; ++k) {
      const float4 a = *(const float4*)&Qt[k][r0];
      const float4 bb = *(const float4*)&Kt[k][c0];
      const float av[4] = {a.x, a.y, a.z, a.w};
      const float bv[4] = {bb.x, bb.y, bb.z, bb.w};
      #pragma unroll
      for (int i = 0; i < 4; ++i)
        #pragma unroll
        for (int j = 0; j < 4; ++j) sc[i][j] += av[i] * bv[j];
    }
    #pragma unroll
    for (int i = 0; i < 4; ++i) {
      #pragma unroll
      for (int j = 0; j < 4; ++j) sc[i][j] *= 0.125f;   // /sqrt(64), exact
      float tm = fmaxf(fmaxf(sc[i][0], sc[i][1]), fmaxf(sc[i][2], sc[i][3]));
      #pragma unroll
      for (int m = 1; m < 16; m <<= 1) tm = fmaxf(tm, __shfl_xor(tm, m, 16));
      const float mn = fmaxf(m_r[i], tm);
      const float corr = expf(m_r[i] - mn);              // first tile: exp(-inf)=0
      float ts = 0.f;
      #pragma unroll
      for (int j = 0; j < 4; ++j) { sc[i][j] = expf(sc[i][j] - mn); ts += sc[i][j]; }
      #pragma unroll
      for (int m = 1; m < 16; m <<= 1) ts += __shfl_xor(ts, m, 16);
      l_r[i] = l_r[i] * corr + ts;
      m_r[i] = mn;
      #pragma unroll
      for (int j = 0; j < 4; ++j) O[i][j] *= corr;
    }
    #pragma unroll
    for (int j = 0; j < 4; ++j)
      *(float4*)&Pl[c0 + j][r0] = make_float4(sc[0][j], sc[1][j], sc[2][j], sc[3][j]);
    __syncthreads();
    for (int c = 0; c < 64; ++c) {
      const float4 a = *(const float4*)&Pl[c][r0];
      const float4 bb = *(const float4*)&Vl[c][c0];
      const float av[4] = {a.x, a.y, a.z, a.w};
      const float bv[4] = {bb.x, bb.y, bb.z, bb.w};
      #pragma unroll
      for (int i = 0; i < 4; ++i)
        #pragma unroll
        for (int j = 0; j < 4; ++j) O[i][j] += av[i] * bv[j];
    }
  }
  #pragma unroll
  for (int i = 0; i < 4; ++i) {
    const int s = qt * 64 + r0 + i;
    *(float4*)(oa + ((size_t)(b * kS + s) * kH + h) * 64 + c0) =
        make_float4(O[i][0] / l_r[i], O[i][1] / l_r[i], O[i][2] / l_r[i], O[i][3] / l_r[i]);
  }
}

// ------- K3: fused proj + residual + LayerNorm(ddof=1) + lin1/tanh + lin2 ---
__global__ __launch_bounds__(256) void k_head(
    const float* __restrict__ X, const float* __restrict__ oa,
    const float* __restrict__ pw, const float* __restrict__ pb,
    const float* __restrict__ lng, const float* __restrict__ lnb,
    const float* __restrict__ w1, const float* __restrict__ b1,
    const float* __restrict__ w2, const float* __restrict__ b2,
    float* __restrict__ logits)
{
  __shared__ float xl[16][772];
  __shared__ float oal[16][196];
  __shared__ float hl[16][388];
  const int tid = threadIdx.x;
  const int row0 = blockIdx.x * 16;
  {
    const int r = tid >> 4, seg = tid & 15;
    const float* src = X + (size_t)(row0 + r) * kD;
    #pragma unroll
    for (int q = 0; q < 12; ++q) {
      const int c4 = seg + q * 16;
      *(float4*)&xl[r][c4 * 4] = *(const float4*)(src + c4 * 4);
    }
    const float* srco = oa + (size_t)(row0 + r) * 192;
    #pragma unroll
    for (int q = 0; q < 3; ++q) {
      const int c4 = seg + q * 16;
      *(float4*)&oal[r][c4 * 4] = *(const float4*)(srco + c4 * 4);
    }
  }
  __syncthreads();
  #pragma unroll
  for (int pass = 0; pass < 3; ++pass) {
    const int cc = pass * 256 + tid;
    float acc[16] = {};
    for (int k = 0; k < 192; ++k) {
      const float w = pw[(size_t)k * kD + cc];
      #pragma unroll
      for (int r = 0; r < 16; ++r) acc[r] += oal[r][k] * w;
    }
    const float pbv = pb[cc];
    #pragma unroll
    for (int r = 0; r < 16; ++r) xl[r][cc] = acc[r] + pbv + xl[r][cc];
  }
  __syncthreads();
  {
    const int rr = tid >> 4, g = tid & 15;
    float sm = 0.f;
    #pragma unroll
    for (int q = 0; q < 48; ++q) sm += xl[rr][g + q * 16];
    #pragma unroll
    for (int m = 1; m < 16; m <<= 1) sm += __shfl_xor(sm, m, 16);
    const float mu = sm / 768.0f;
    float s2 = 0.f;
    #pragma unroll
    for (int q = 0; q < 48; ++q) { const float d = xl[rr][g + q * 16] - mu; s2 += d * d; }
    #pragma unroll
    for (int m = 1; m < 16; m <<= 1) s2 += __shfl_xor(s2, m, 16);
    const float den = sqrtf(s2 / 767.0f) + 1e-3f;   // std(ddof=1) + eps
    #pragma unroll
    for (int q = 0; q < 48; ++q) {
      const int c = g + q * 16;
      xl[rr][c] = (xl[rr][c] - mu) / den * lng[c] + lnb[c];
    }
  }
  __syncthreads();
  #pragma unroll
  for (int pass = 0; pass < 2; ++pass) {
    const int cc = pass * 256 + tid;
    if (cc < 384) {
      float acc[16] = {};
      for (int k = 0; k < 768; ++k) {
        const float w = w1[(size_t)k * 384 + cc];
        #pragma unroll
        for (int r = 0; r < 16; ++r) acc[r] += xl[r][k] * w;
      }
      const float bv = b1[cc];
      #pragma unroll
      for (int r = 0; r < 16; ++r) hl[r][cc] = tanhf(acc[r] + bv);
    }
  }
  __syncthreads();
  for (int idx = tid; idx < 16 * kTAG; idx += 256) {
    const int r = idx / kTAG, j = idx - r * kTAG;
    float acc = 0.f;
    for (int k = 0; k < 384; ++k) acc += hl[r][k] * w2[(size_t)k * kTAG + j];
    logits[(size_t)(row0 + r) * kTAG + j] = acc + b2[j];
  }
}

// ---------------- K4: Viterbi beam DP (exact top-k with jax tie-breaking) ---
__device__ __forceinline__ unsigned long long vk_key(float v, int idx) {
  unsigned u = __float_as_uint(v);
  u = (u & 0x80000000u) ? ~u : (u | 0x80000000u);
  return ((unsigned long long)u << 32) | (unsigned)(~idx);  // value desc, idx asc
}
__device__ __forceinline__ float vk_val(unsigned long long k) {
  unsigned u = (unsigned)(k >> 32);
  u = (u & 0x80000000u) ? (u & 0x7fffffffu) : ~u;
  return __uint_as_float(u);
}
__device__ __forceinline__ int vk_idx(unsigned long long k) {
  return (int)(~(unsigned)k);
}
__device__ __forceinline__ unsigned long long shfl_xor_u64_w8(unsigned long long v, int m) {
  const int lo = __shfl_xor((int)(unsigned)v, m, 8);
  const int hi = __shfl_xor((int)(unsigned)(v >> 32), m, 8);
  return ((unsigned long long)(unsigned)hi << 32) | (unsigned)lo;
}

template <bool FINAL>
__device__ __forceinline__ void topk_rounds(
    int g, float s0, float s1, float s2, float s3, float s4,
    const float (*pin)[kNB], float* outval, unsigned short* outbp, int mt, int* outptr)
{
  const float scv[5] = {s0, s1, s2, s3, s4};
  unsigned long long key[5];
  int nn[5];
  #pragma unroll
  for (int c = 0; c < 5; ++c) {
    const int i = g + 8 * c;
    if (i < kTAG) { nn[c] = 0; key[c] = vk_key(scv[c] + pin[i][0], i * 8); }
    else { nn[c] = 8; key[c] = 0ULL; }
  }
  unsigned long long bk = key[0];
  #pragma unroll
  for (int c = 1; c < 5; ++c) bk = (bk > key[c]) ? bk : key[c];
  #pragma unroll
  for (int r = 0; r < 8; ++r) {
    unsigned long long w = bk, o;
    o = shfl_xor_u64_w8(w, 1); w = (w > o) ? w : o;
    o = shfl_xor_u64_w8(w, 2); w = (w > o) ? w : o;
    o = shfl_xor_u64_w8(w, 4); w = (w > o) ? w : o;
    if (bk == w) {                       // unique owner (keys unique by idx)
      const int idx = vk_idx(w);
      if constexpr (FINAL) { outptr[r] = idx; }
      else { outval[r] = vk_val(w); outbp[r] = (unsigned short)(mt ? idx : 0); }
      #pragma unroll
      for (int c = 0; c < 5; ++c) {
        if (key[c] == w) {
          const int i = g + 8 * c;
          const int n = ++nn[c];
          key[c] = (n < 8) ? vk_key(scv[c] + pin[i][n], i * 8 + n) : 0ULL;
        }
      }
      bk = key[0];
      #pragma unroll
      for (int c = 1; c < 5; ++c) bk = (bk > key[c]) ? bk : key[c];
    }
  }
}

__global__ __launch_bounds__(320) void k_viterbi(
    const float* __restrict__ logits, const int* __restrict__ mask,
    const float* __restrict__ trans, unsigned short* __restrict__ bps,
    int* __restrict__ lastpos_g, int* __restrict__ ptr0_g)
{
  __shared__ float trans_s[kTAG][kTAG];
  __shared__ float part[2][kTAG][kNB];
  __shared__ float lastp[kTAG][kNB];
  __shared__ float logit_s[kTAG];
  __shared__ int lastpos_s;
  const int b = blockIdx.x;
  const int tid = threadIdx.x;
  for (int idx = tid; idx < kTAG * kTAG; idx += 320)
    trans_s[idx / kTAG][idx % kTAG] = trans[idx];
  if (tid < 64) {
    int sm = 0;
    #pragma unroll
    for (int q = 0; q < 8; ++q) sm += mask[b * kS + tid * 8 + q];
    #pragma unroll
    for (int m = 1; m < 64; m <<= 1) sm += __shfl_xor(sm, m, 64);
    if (tid == 0) { lastpos_s = sm - 1; lastpos_g[b] = sm - 1; }
  }
  if (tid < kTAG) logit_s[tid] = logits[(size_t)b * kS * kTAG + tid];
  __syncthreads();
  if (tid < kTAG * kNB) {
    const int jj = tid >> 3, n = tid & 7;
    part[0][jj][n] = (n == 0) ? (logit_s[jj] + trans_s[kSTART][jj]) : kNEG;
  }
  const int j = tid >> 3, g = tid & 7;
  for (int t = 1; t < kS; ++t) {
    __syncthreads();
    const int pr = (t - 1) & 1, pw2 = t & 1;
    if ((t - 1) == lastpos_s && tid < kTAG * kNB)
      lastp[tid >> 3][tid & 7] = part[pr][tid >> 3][tid & 7];
    if (tid < kTAG) logit_s[tid] = logits[(size_t)(b * kS + t) * kTAG + tid];
    __syncthreads();
    if (tid < kTAG * kNB) {
      const int mt = mask[b * kS + t];
      const float lg = logit_s[j];
      float s[5];
      #pragma unroll
      for (int c = 0; c < 5; ++c) {
        const int i = g + 8 * c;
        s[c] = (i < kTAG) ? (lg + trans_s[i][j]) : 0.f;   // scores first, then +partition
      }
      unsigned short* bprow = bps + ((size_t)t * kB + b) * (kTAG * kNB) + j * kNB;
      topk_rounds<false>(g, s[0], s[1], s[2], s[3], s[4], part[pr],
                         &part[pw2][j][0], bprow, mt, nullptr);
    }
  }
  __syncthreads();
  if (lastpos_s == kS - 1 && tid < kTAG * kNB)
    lastp[tid >> 3][tid & 7] = part[(kS - 1) & 1][tid >> 3][tid & 7];
  __syncthreads();
  if (j == kSTOP && tid < kTAG * kNB) {   // pointer0 = end_bp[:, STOP, :]
    float s[5];
    #pragma unroll
    for (int c = 0; c < 5; ++c) {
      const int i = g + 8 * c;
      s[c] = (i < kTAG) ? trans_s[i][kSTOP] : 0.f;
    }
    topk_rounds<true>(g, s[0], s[1], s[2], s[3], s[4], lastp,
                      nullptr, nullptr, 0, ptr0_g + b * kNB);
  }
}

// ---------------- K5: backtrace (slot-0 chain only feeds the output) --------
__global__ __launch_bounds__(64) void k_backtrace(
    const unsigned short* __restrict__ bps, const int* __restrict__ ptr0,
    const int* __restrict__ lastpos, const int* __restrict__ mask,
    int* __restrict__ out)
{
  const int b = threadIdx.x;
  const int lp = lastpos[b];
  int p = ptr0[b * kNB];
  out[b * kS + kS - 1] = p >> 3;
  for (int tau = kS - 2; tau >= 0; --tau) {
    int np;
    if (tau == lp) np = ptr0[b * kNB + (p & 7)];          // ins replacement row
    else np = bps[((size_t)(tau + 1) * kB + b) * (kTAG * kNB) + p];
    const int m = mask[b * kS + tau];
    out[b * kS + tau] = np >> 3;
    p = m ? np : (np + p);                                 // carry = new_p + p*inv
  }
}

extern "C" void kernel_launch(void* const* d_in, const int* in_sizes, int n_in,
                              void* d_out, int out_size, void* d_ws, size_t ws_size,
                              hipStream_t stream) {
  if (ws_size < kWsNeed) return;  // fail loudly rather than corrupt memory
  const float* X   = (const float*)d_in[0];
  const int*   msk = (const int*)d_in[1];
  const float* wq  = (const float*)d_in[2];
  const float* wk  = (const float*)d_in[3];
  const float* wv  = (const float*)d_in[4];
  const float* pw  = (const float*)d_in[5];
  const float* pb  = (const float*)d_in[6];
  const float* lng = (const float*)d_in[7];
  const float* lnb = (const float*)d_in[8];
  const float* w1  = (const float*)d_in[9];
  const float* b1  = (const float*)d_in[10];
  const float* w2  = (const float*)d_in[11];
  const float* b2  = (const float*)d_in[12];
  const float* trn = (const float*)d_in[13];
  float* ws = (float*)d_ws;

  k_qkv<<<dim3(9, 256), 256, 0, stream>>>(X, wq, wk, wv, ws);
  k_attn<<<dim3(8, 3, 64), 256, 0, stream>>>(ws + kQOFF, ws + kKOFF, ws + kVOFF, ws + kOAOFF);
  k_head<<<2048, 256, 0, stream>>>(X, ws + kOAOFF, pw, pb, lng, lnb, w1, b1, w2, b2, ws);
  unsigned short* bps = (unsigned short*)((char*)d_ws + kBpsByte);
  int* lastpos_p = (int*)(ws + kKOFF);   // K buffer dead after attention
  int* ptr0_p = lastpos_p + kB;
  k_viterbi<<<kB, 320, 0, stream>>>(ws, msk, trn, bps, lastpos_p, ptr0_p);
  k_backtrace<<<1, 64, 0, stream>>>(bps, ptr0_p, lastpos_p, msk, (int*)d_out);
}

// Round 2
// 4209.026 us; speedup vs baseline: 1.1422x; 1.1422x over previous
//
#include <hip/hip_runtime.h>
#include <stdint.h>

namespace {
constexpr int kB = 64, kS = 512, kD = 768, kH = 3, kDK = 64;
constexpr int kTAG = 33, kNB = 8, kSTART = 31, kSTOP = 32;
constexpr float kNEG = -1e30f;
constexpr size_t kHead = (size_t)kB * kH * kS * kDK;      // 6,291,456 floats per Q/K/V/OA buffer
constexpr size_t kQOFF = 0, kKOFF = kHead, kVOFF = 2 * kHead, kOAOFF = 3 * kHead;
constexpr size_t kWsNeed = 4 * kHead * sizeof(float);     // ~100.7 MB
constexpr size_t kBpsByte = (size_t)kB * kS * kTAG * 4;   // BPS (u16) byte offset inside dead Q region
}

// ---------------- K1: QKV projection, f32 SIMT GEMM (BM=128,BN=64,BK=16) ----
__global__ __launch_bounds__(256) void k_qkv(
    const float* __restrict__ X, const float* __restrict__ wq,
    const float* __restrict__ wk, const float* __restrict__ wv,
    float* __restrict__ ws)
{
  __shared__ float As[16][132];
  __shared__ float Bs[16][68];
  const int bx = blockIdx.x;            // 0..8 -> (type, head)
  const int m0 = blockIdx.y * 128;
  const int tid = threadIdx.x;
  const int tx = tid & 15, ty = tid >> 4;
  const int typ = bx / 3, h = bx % 3;
  const float* wptr = (typ == 0) ? wq : (typ == 1) ? wk : wv;
  float* outp = ws + ((typ == 0) ? kQOFF : (typ == 1) ? kKOFF : kVOFF);

  float acc[8][4] = {};
  const int rowA = tid >> 2, ka = (tid & 3) * 4;
  const int rowB = tid >> 6, cb = tid & 63;
  for (int k0 = 0; k0 < kD; k0 += 16) {
    #pragma unroll
    for (int half = 0; half < 2; ++half) {
      const int r = rowA + half * 64;
      const float4 v = *(const float4*)(X + (size_t)(m0 + r) * kD + k0 + ka);
      As[ka + 0][r] = v.x; As[ka + 1][r] = v.y; As[ka + 2][r] = v.z; As[ka + 3][r] = v.w;
    }
    #pragma unroll
    for (int q = 0; q < 4; ++q) {
      const int k = rowB + q * 4;
      Bs[k][cb] = wptr[((size_t)h * kD + k0 + k) * 64 + cb];
    }
    __syncthreads();
    #pragma unroll
    for (int kk = 0; kk < 16; ++kk) {
      const float4 a0 = *(const float4*)&As[kk][ty * 8];
      const float4 a1 = *(const float4*)&As[kk][ty * 8 + 4];
      const float4 b0 = *(const float4*)&Bs[kk][tx * 4];
      const float a[8] = {a0.x, a0.y, a0.z, a0.w, a1.x, a1.y, a1.z, a1.w};
      const float bv[4] = {b0.x, b0.y, b0.z, b0.w};
      #pragma unroll
      for (int i = 0; i < 8; ++i)
        #pragma unroll
        for (int j = 0; j < 4; ++j) acc[i][j] += a[i] * bv[j];
    }
    __syncthreads();
  }
  #pragma unroll
  for (int i = 0; i < 8; ++i) {
    const int m = m0 + ty * 8 + i;
    const int b = m >> 9, s = m & 511;
    *(float4*)(outp + ((size_t)(b * kH + h) * kS + s) * kDK + tx * 4) =
        make_float4(acc[i][0], acc[i][1], acc[i][2], acc[i][3]);
  }
}

// ---------------- K2: flash-style attention, 64 q-rows per block ------------
__global__ __launch_bounds__(256) void k_attn(
    const float* __restrict__ Q, const float* __restrict__ K,
    const float* __restrict__ V, float* __restrict__ oa)
{
  __shared__ float Qt[64][68];
  __shared__ float Kt[64][68];
  __shared__ float Vl[64][68];
  __shared__ float Pl[64][68];
  const int qt = blockIdx.x, h = blockIdx.y, b = blockIdx.z;
  const int tid = threadIdx.x;
  const int tx = tid & 15, ty = tid >> 4;
  const int r0 = ty * 4, c0 = tx * 4;
  const size_t base = (size_t)(b * kH + h) * kS * kDK;

  {
    const int row = tid >> 2, cc = (tid & 3) * 4;
    const float* src = Q + base + (size_t)(qt * 64 + row) * kDK;
    #pragma unroll
    for (int q = 0; q < 4; ++q) {
      const int c = cc + q * 16;
      const float4 v = *(const float4*)(src + c);
      Qt[c + 0][row] = v.x; Qt[c + 1][row] = v.y; Qt[c + 2][row] = v.z; Qt[c + 3][row] = v.w;
    }
  }
  float m_r[4], l_r[4], O[4][4];
  #pragma unroll
  for (int i = 0; i < 4; ++i) {
    m_r[i] = -__builtin_huge_valf(); l_r[i] = 0.f;
    #pragma unroll
    for (int j = 0; j < 4; ++j) O[i][j] = 0.f;
  }
  for (int kt = 0; kt < 8; ++kt) {
    __syncthreads();
    {
      const int row = tid >> 2, cc = (tid & 3) * 4;
      const float* srck = K + base + (size_t)(kt * 64 + row) * kDK;
      const float* srcv = V + base + (size_t)(kt * 64 + row) * kDK;
      #pragma unroll
      for (int q = 0; q < 4; ++q) {
        const int c = cc + q * 16;
        const float4 v = *(const float4*)(srck + c);
        Kt[c + 0][row] = v.x; Kt[c + 1][row] = v.y; Kt[c + 2][row] = v.z; Kt[c + 3][row] = v.w;
        *(float4*)&Vl[row][c] = *(const float4*)(srcv + c);
      }
    }
    __syncthreads();
    float sc[4][4] = {};
    for (int k = 0; k < 64; ++k) {
      const float4 a = *(const float4*)&Qt[k][r0];
      const float4 bb = *(const float4*)&Kt[k][c0];
      const float av[4] = {a.x, a.y, a.z, a.w};
      const float bv[4] = {bb.x, bb.y, bb.z, bb.w};
      #pragma unroll
      for (int i = 0; i < 4; ++i)
        #pragma unroll
        for (int j = 0; j < 4; ++j) sc[i][j] += av[i] * bv[j];
    }
    #pragma unroll
    for (int i = 0; i < 4; ++i) {
      #pragma unroll
      for (int j = 0; j < 4; ++j) sc[i][j] *= 0.125f;   // /sqrt(64), exact
      float tm = fmaxf(fmaxf(sc[i][0], sc[i][1]), fmaxf(sc[i][2], sc[i][3]));
      #pragma unroll
      for (int m = 1; m < 16; m <<= 1) tm = fmaxf(tm, __shfl_xor(tm, m, 16));
      const float mn = fmaxf(m_r[i], tm);
      const float corr = expf(m_r[i] - mn);              // first tile: exp(-inf)=0
      float ts = 0.f;
      #pragma unroll
      for (int j = 0; j < 4; ++j) { sc[i][j] = expf(sc[i][j] - mn); ts += sc[i][j]; }
      #pragma unroll
      for (int m = 1; m < 16; m <<= 1) ts += __shfl_xor(ts, m, 16);
      l_r[i] = l_r[i] * corr + ts;
      m_r[i] = mn;
      #pragma unroll
      for (int j = 0; j < 4; ++j) O[i][j] *= corr;
    }
    #pragma unroll
    for (int j = 0; j < 4; ++j)
      *(float4*)&Pl[c0 + j][r0] = make_float4(sc[0][j], sc[1][j], sc[2][j], sc[3][j]);
    __syncthreads();
    for (int c = 0; c < 64; ++c) {
      const float4 a = *(const float4*)&Pl[c][r0];
      const float4 bb = *(const float4*)&Vl[c][c0];
      const float av[4] = {a.x, a.y, a.z, a.w};
      const float bv[4] = {bb.x, bb.y, bb.z, bb.w};
      #pragma unroll
      for (int i = 0; i < 4; ++i)
        #pragma unroll
        for (int j = 0; j < 4; ++j) O[i][j] += av[i] * bv[j];
    }
  }
  #pragma unroll
  for (int i = 0; i < 4; ++i) {
    const int s = qt * 64 + r0 + i;
    *(float4*)(oa + ((size_t)(b * kS + s) * kH + h) * 64 + c0) =
        make_float4(O[i][0] / l_r[i], O[i][1] / l_r[i], O[i][2] / l_r[i], O[i][3] / l_r[i]);
  }
}

// ------- K3: fused proj + residual + LayerNorm(ddof=1) + lin1/tanh + lin2 ---
__global__ __launch_bounds__(256) void k_head(
    const float* __restrict__ X, const float* __restrict__ oa,
    const float* __restrict__ pw, const float* __restrict__ pb,
    const float* __restrict__ lng, const float* __restrict__ lnb,
    const float* __restrict__ w1, const float* __restrict__ b1,
    const float* __restrict__ w2, const float* __restrict__ b2,
    float* __restrict__ logits)
{
  __shared__ float xl[16][772];
  __shared__ float oal[16][196];
  __shared__ float hl[16][388];
  const int tid = threadIdx.x;
  const int row0 = blockIdx.x * 16;
  {
    const int r = tid >> 4, seg = tid & 15;
    const float* src = X + (size_t)(row0 + r) * kD;
    #pragma unroll
    for (int q = 0; q < 12; ++q) {
      const int c4 = seg + q * 16;
      *(float4*)&xl[r][c4 * 4] = *(const float4*)(src + c4 * 4);
    }
    const float* srco = oa + (size_t)(row0 + r) * 192;
    #pragma unroll
    for (int q = 0; q < 3; ++q) {
      const int c4 = seg + q * 16;
      *(float4*)&oal[r][c4 * 4] = *(const float4*)(srco + c4 * 4);
    }
  }
  __syncthreads();
  #pragma unroll
  for (int pass = 0; pass < 3; ++pass) {
    const int cc = pass * 256 + tid;
    float acc[16] = {};
    for (int k = 0; k < 192; ++k) {
      const float w = pw[(size_t)k * kD + cc];
      #pragma unroll
      for (int r = 0; r < 16; ++r) acc[r] += oal[r][k] * w;
    }
    const float pbv = pb[cc];
    #pragma unroll
    for (int r = 0; r < 16; ++r) xl[r][cc] = acc[r] + pbv + xl[r][cc];
  }
  __syncthreads();
  {
    const int rr = tid >> 4, g = tid & 15;
    float sm = 0.f;
    #pragma unroll
    for (int q = 0; q < 48; ++q) sm += xl[rr][g + q * 16];
    #pragma unroll
    for (int m = 1; m < 16; m <<= 1) sm += __shfl_xor(sm, m, 16);
    const float mu = sm / 768.0f;
    float s2 = 0.f;
    #pragma unroll
    for (int q = 0; q < 48; ++q) { const float d = xl[rr][g + q * 16] - mu; s2 += d * d; }
    #pragma unroll
    for (int m = 1; m < 16; m <<= 1) s2 += __shfl_xor(s2, m, 16);
    const float den = sqrtf(s2 / 767.0f) + 1e-3f;   // std(ddof=1) + eps
    #pragma unroll
    for (int q = 0; q < 48; ++q) {
      const int c = g + q * 16;
      xl[rr][c] = (xl[rr][c] - mu) / den * lng[c] + lnb[c];
    }
  }
  __syncthreads();
  #pragma unroll
  for (int pass = 0; pass < 2; ++pass) {
    const int cc = pass * 256 + tid;
    if (cc < 384) {
      float acc[16] = {};
      for (int k = 0; k < 768; ++k) {
        const float w = w1[(size_t)k * 384 + cc];
        #pragma unroll
        for (int r = 0; r < 16; ++r) acc[r] += xl[r][k] * w;
      }
      const float bv = b1[cc];
      #pragma unroll
      for (int r = 0; r < 16; ++r) hl[r][cc] = tanhf(acc[r] + bv);
    }
  }
  __syncthreads();
  for (int idx = tid; idx < 16 * kTAG; idx += 256) {
    const int r = idx / kTAG, j = idx - r * kTAG;
    float acc = 0.f;
    for (int k = 0; k < 384; ++k) acc += hl[r][k] * w2[(size_t)k * kTAG + j];
    logits[(size_t)(row0 + r) * kTAG + j] = acc + b2[j];
  }
}

// ---------------- K4: Viterbi beam DP (exact top-k, DPP-based merge) --------
__device__ __forceinline__ unsigned long long vk_key(float v, int idx) {
  unsigned u = __float_as_uint(v);
  u = (u & 0x80000000u) ? ~u : (u | 0x80000000u);
  return ((unsigned long long)u << 32) | (unsigned)(~idx);  // value desc, idx asc
}
__device__ __forceinline__ float vk_val(unsigned long long k) {
  unsigned u = (unsigned)(k >> 32);
  u = (u & 0x80000000u) ? (u & 0x7fffffffu) : ~u;
  return __uint_as_float(u);
}
__device__ __forceinline__ int vk_idx(unsigned long long k) {
  return (int)(~(unsigned)k);
}
__device__ __forceinline__ unsigned long long u64pack(unsigned lo, unsigned hi) {
  return ((unsigned long long)hi << 32) | lo;
}
// max over each aligned 8-lane group, via VALU-latency DPP (xor1, xor2, lane^7)
__device__ __forceinline__ unsigned long long dpp8_max(unsigned long long v) {
  unsigned lo = (unsigned)v, hi = (unsigned)(v >> 32);
  {
    unsigned a = (unsigned)__builtin_amdgcn_update_dpp((int)lo, (int)lo, 0xB1, 0xF, 0xF, false);
    unsigned c = (unsigned)__builtin_amdgcn_update_dpp((int)hi, (int)hi, 0xB1, 0xF, 0xF, false);
    if (u64pack(a, c) > u64pack(lo, hi)) { lo = a; hi = c; }
  }
  {
    unsigned a = (unsigned)__builtin_amdgcn_update_dpp((int)lo, (int)lo, 0x4E, 0xF, 0xF, false);
    unsigned c = (unsigned)__builtin_amdgcn_update_dpp((int)hi, (int)hi, 0x4E, 0xF, 0xF, false);
    if (u64pack(a, c) > u64pack(lo, hi)) { lo = a; hi = c; }
  }
  {
    unsigned a = (unsigned)__builtin_amdgcn_update_dpp((int)lo, (int)lo, 0x141, 0xF, 0xF, false);
    unsigned c = (unsigned)__builtin_amdgcn_update_dpp((int)hi, (int)hi, 0x141, 0xF, 0xF, false);
    if (u64pack(a, c) > u64pack(lo, hi)) { lo = a; hi = c; }
  }
  return u64pack(lo, hi);
}
// select element n (0..7) from two float4s with a static cndmask tree (no scratch)
__device__ __forceinline__ float sel8(float4 a, float4 b, int n) {
  const float x01 = (n & 1) ? a.y : a.x;
  const float x23 = (n & 1) ? a.w : a.z;
  const float x45 = (n & 1) ? b.y : b.x;
  const float x67 = (n & 1) ? b.w : b.z;
  const float lo = (n & 2) ? x23 : x01;
  const float hi = (n & 2) ? x67 : x45;
  return (n & 4) ? hi : lo;
}

__global__ __launch_bounds__(320) void k_viterbi(
    const float* __restrict__ logits, const int* __restrict__ mask,
    const float* __restrict__ trans, unsigned short* __restrict__ bps,
    int* __restrict__ lastpos_g, int* __restrict__ ptr0_g)
{
  __shared__ __align__(16) float trans_s[kTAG][kTAG];
  __shared__ __align__(16) float part[2][kTAG][kNB];
  __shared__ __align__(16) float lastp[kTAG][kNB];
  __shared__ int mask_s[kS];
  __shared__ int lastpos_s;
  const int b = blockIdx.x, tid = threadIdx.x;
  for (int idx = tid; idx < kTAG * kTAG; idx += 320)
    trans_s[idx / kTAG][idx % kTAG] = trans[idx];
  for (int idx = tid; idx < kS; idx += 320) mask_s[idx] = mask[b * kS + idx];
  if (tid < 64) {
    int sm = 0;
    #pragma unroll
    for (int q = 0; q < 8; ++q) sm += mask[b * kS + tid * 8 + q];
    #pragma unroll
    for (int m = 1; m < 64; m <<= 1) sm += __shfl_xor(sm, m, 64);
    if (tid == 0) { lastpos_s = sm - 1; lastpos_g[b] = sm - 1; }
  }
  __syncthreads();
  const bool active = (tid < kTAG * kNB);
  const int j = tid >> 3, g = tid & 7;
  const int jc = (j < kTAG) ? j : (kTAG - 1);
  int ii[5]; bool valid[5]; float tr[5];
  #pragma unroll
  for (int c = 0; c < 5; ++c) {
    const int i0 = g + 8 * c;
    valid[c] = active && (i0 < kTAG);
    ii[c] = (i0 < kTAG) ? i0 : (kTAG - 1);
    tr[c] = trans_s[ii[c]][jc];
  }
  if (active)
    part[0][j][g] = (g == 0) ? (logits[(size_t)b * kS * kTAG + j] + trans_s[kSTART][j]) : kNEG;
  float lg_next = logits[((size_t)b * kS + 1) * kTAG + jc];
  __syncthreads();

  for (int t = 1; t < kS; ++t) {
    const int pr = (t - 1) & 1, pw = t & 1;
    const int mt = mask_s[t];
    if ((t - 1) == lastpos_s && active) lastp[j][g] = part[pr][j][g];
    const float lg = lg_next;
    if (t < kS - 1) lg_next = logits[((size_t)b * kS + t + 1) * kTAG + jc];
    float4 pA[5], pB[5]; unsigned long long key[5]; int nn[5]; float s[5];
    #pragma unroll
    for (int c = 0; c < 5; ++c) {
      const float4* prow = (const float4*)&part[pr][ii[c]][0];
      pA[c] = prow[0]; pB[c] = prow[1];
      s[c] = lg + tr[c];
      if (valid[c]) { nn[c] = 0; key[c] = vk_key(s[c] + pA[c].x, ii[c] * kNB); }
      else { nn[c] = 8; key[c] = 0ULL; }
    }
    unsigned short* bprow = bps + ((size_t)t * kB + b) * (kTAG * kNB) + jc * kNB;
    #pragma unroll
    for (int r = 0; r < 8; ++r) {
      unsigned long long bk = key[0];
      #pragma unroll
      for (int c = 1; c < 5; ++c) bk = (key[c] > bk) ? key[c] : bk;
      const unsigned long long w = dpp8_max(bk);
      if (active && bk == w) {
        part[pw][j][r] = vk_val(w);
        bprow[r] = (unsigned short)(mt ? vk_idx(w) : 0);
      }
      if (r < 7) {
        #pragma unroll
        for (int c = 0; c < 5; ++c) {
          if (key[c] == w && key[c] != 0ULL) {
            const int n = ++nn[c];
            key[c] = (n < kNB) ? vk_key(s[c] + sel8(pA[c], pB[c], n), ii[c] * kNB + n) : 0ULL;
          }
        }
      }
    }
    __syncthreads();
  }
  if (lastpos_s == kS - 1 && active) lastp[j][g] = part[(kS - 1) & 1][j][g];
  __syncthreads();
  if (j == kSTOP) {   // lanes 256..263 exactly (one aligned 8-group)
    float4 pA[5], pB[5]; unsigned long long key[5]; int nn[5];
    #pragma unroll
    for (int c = 0; c < 5; ++c) {
      const float4* prow = (const float4*)&lastp[ii[c]][0];
      pA[c] = prow[0]; pB[c] = prow[1];
      if (valid[c]) { nn[c] = 0; key[c] = vk_key(tr[c] + pA[c].x, ii[c] * kNB); }
      else { nn[c] = 8; key[c] = 0ULL; }
    }
    #pragma unroll
    for (int r = 0; r < 8; ++r) {
      unsigned long long bk = key[0];
      #pragma unroll
      for (int c = 1; c < 5; ++c) bk = (key[c] > bk) ? key[c] : bk;
      const unsigned long long w = dpp8_max(bk);
      if (bk == w) ptr0_g[b * kNB + r] = vk_idx(w);
      if (r < 7) {
        #pragma unroll
        for (int c = 0; c < 5; ++c) {
          if (key[c] == w && key[c] != 0ULL) {
            const int n = ++nn[c];
            key[c] = (n < kNB) ? vk_key(tr[c] + sel8(pA[c], pB[c], n), ii[c] * kNB + n) : 0ULL;
          }
        }
      }
    }
  }
}

// ------- K5: backtrace, per-batch block with LDS-prefetched bp rows ---------
__global__ __launch_bounds__(256) void k_backtrace(
    const unsigned short* __restrict__ bps, const int* __restrict__ ptr0,
    const int* __restrict__ lastpos, const int* __restrict__ mask,
    int* __restrict__ out)
{
  __shared__ uint4 buf[2][4][33];          // 4 rows x 264 u16 per stage
  __shared__ int ptr0_s[kNB];
  __shared__ int mask_s[kS];
  const int b = blockIdx.x, tid = threadIdx.x;
  if (tid < kNB) ptr0_s[tid] = ptr0[b * kNB + tid];
  for (int i = tid; i < kS; i += 256) mask_s[i] = mask[b * kS + i];
  const int lp = lastpos[b];
  const int lr = tid / 33, lc = tid % 33;
  if (tid < 132)
    buf[0][lr][lc] = ((const uint4*)(bps + ((size_t)(kS - 1 - lr) * kB + b) * (kTAG * kNB)))[lc];
  int p = ptr0[b * kNB];
  if (tid == 0) out[b * kS + kS - 1] = p >> 3;
  __syncthreads();
  int cur = 0, tau = kS - 2;
  while (tau >= 0) {
    const int cnt = (tau >= 3) ? 4 : (tau + 1);
    const int ntau = tau - cnt;
    uint4 v; bool have = false;
    if (ntau >= 0 && tid < 132) {
      const int cnt2 = (ntau >= 3) ? 4 : (ntau + 1);
      if (lr < cnt2) {
        v = ((const uint4*)(bps + ((size_t)(ntau + 1 - lr) * kB + b) * (kTAG * kNB)))[lc];
        have = true;
      }
    }
    for (int s2 = 0; s2 < cnt; ++s2) {
      const int t2 = tau - s2;
      int np;
      if (t2 == lp) np = ptr0_s[p & 7];
      else np = ((const unsigned short*)&buf[cur][s2][0])[p];
      if (tid == 0) out[b * kS + t2] = np >> 3;
      p = mask_s[t2] ? np : (np + p);
    }
    __syncthreads();
    if (have) buf[cur ^ 1][lr][lc] = v;
    __syncthreads();
    cur ^= 1; tau = ntau;
  }
}

extern "C" void kernel_launch(void* const* d_in, const int* in_sizes, int n_in,
                              void* d_out, int out_size, void* d_ws, size_t ws_size,
                              hipStream_t stream) {
  if (ws_size < kWsNeed) return;  // fail loudly rather than corrupt memory
  const float* X   = (const float*)d_in[0];
  const int*   msk = (const int*)d_in[1];
  const float* wq  = (const float*)d_in[2];
  const float* wk  = (const float*)d_in[3];
  const float* wv  = (const float*)d_in[4];
  const float* pw  = (const float*)d_in[5];
  const float* pb  = (const float*)d_in[6];
  const float* lng = (const float*)d_in[7];
  const float* lnb = (const float*)d_in[8];
  const float* w1  = (const float*)d_in[9];
  const float* b1  = (const float*)d_in[10];
  const float* w2  = (const float*)d_in[11];
  const float* b2  = (const float*)d_in[12];
  const float* trn = (const float*)d_in[13];
  float* ws = (float*)d_ws;

  k_qkv<<<dim3(9, 256), 256, 0, stream>>>(X, wq, wk, wv, ws);
  k_attn<<<dim3(8, 3, 64), 256, 0, stream>>>(ws + kQOFF, ws + kKOFF, ws + kVOFF, ws + kOAOFF);
  k_head<<<2048, 256, 0, stream>>>(X, ws + kOAOFF, pw, pb, lng, lnb, w1, b1, w2, b2, ws);
  unsigned short* bps = (unsigned short*)((char*)d_ws + kBpsByte);
  int* lastpos_p = (int*)(ws + kKOFF);   // K buffer dead after attention
  int* ptr0_p = lastpos_p + kB;
  k_viterbi<<<kB, 320, 0, stream>>>(ws, msk, trn, bps, lastpos_p, ptr0_p);
  k_backtrace<<<kB, 256, 0, stream>>>(bps, ptr0_p, lastpos_p, msk, (int*)d_out);
}

// Round 3
// 3474.437 us; speedup vs baseline: 1.3837x; 1.2114x over previous
//
#include <hip/hip_runtime.h>
#include <stdint.h>

namespace {
constexpr int kB = 64, kS = 512, kD = 768, kH = 3, kDK = 64;
constexpr int kTAG = 33, kNB = 8, kSTART = 31, kSTOP = 32;
constexpr float kNEG = -1e30f;
constexpr size_t kHead = (size_t)kB * kH * kS * kDK;      // 6,291,456 floats per Q/K/V/OA buffer
constexpr size_t kQOFF = 0, kKOFF = kHead, kVOFF = 2 * kHead, kOAOFF = 3 * kHead;
constexpr size_t kWsNeed = 4 * kHead * sizeof(float);     // ~100.7 MB
constexpr size_t kBpsByte = (size_t)kB * kS * kTAG * 4;   // BPS (u16) byte offset inside dead Q region
}

// ---------------- K1: QKV projection, f32 SIMT GEMM (BM=128,BN=64,BK=16) ----
__global__ __launch_bounds__(256) void k_qkv(
    const float* __restrict__ X, const float* __restrict__ wq,
    const float* __restrict__ wk, const float* __restrict__ wv,
    float* __restrict__ ws)
{
  __shared__ float As[16][132];
  __shared__ float Bs[16][68];
  const int bx = blockIdx.x;            // 0..8 -> (type, head)
  const int m0 = blockIdx.y * 128;
  const int tid = threadIdx.x;
  const int tx = tid & 15, ty = tid >> 4;
  const int typ = bx / 3, h = bx % 3;
  const float* wptr = (typ == 0) ? wq : (typ == 1) ? wk : wv;
  float* outp = ws + ((typ == 0) ? kQOFF : (typ == 1) ? kKOFF : kVOFF);

  float acc[8][4] = {};
  const int rowA = tid >> 2, ka = (tid & 3) * 4;
  const int rowB = tid >> 6, cb = tid & 63;
  for (int k0 = 0; k0 < kD; k0 += 16) {
    #pragma unroll
    for (int half = 0; half < 2; ++half) {
      const int r = rowA + half * 64;
      const float4 v = *(const float4*)(X + (size_t)(m0 + r) * kD + k0 + ka);
      As[ka + 0][r] = v.x; As[ka + 1][r] = v.y; As[ka + 2][r] = v.z; As[ka + 3][r] = v.w;
    }
    #pragma unroll
    for (int q = 0; q < 4; ++q) {
      const int k = rowB + q * 4;
      Bs[k][cb] = wptr[((size_t)h * kD + k0 + k) * 64 + cb];
    }
    __syncthreads();
    #pragma unroll
    for (int kk = 0; kk < 16; ++kk) {
      const float4 a0 = *(const float4*)&As[kk][ty * 8];
      const float4 a1 = *(const float4*)&As[kk][ty * 8 + 4];
      const float4 b0 = *(const float4*)&Bs[kk][tx * 4];
      const float a[8] = {a0.x, a0.y, a0.z, a0.w, a1.x, a1.y, a1.z, a1.w};
      const float bv[4] = {b0.x, b0.y, b0.z, b0.w};
      #pragma unroll
      for (int i = 0; i < 8; ++i)
        #pragma unroll
        for (int j = 0; j < 4; ++j) acc[i][j] += a[i] * bv[j];
    }
    __syncthreads();
  }
  #pragma unroll
  for (int i = 0; i < 8; ++i) {
    const int m = m0 + ty * 8 + i;
    const int b = m >> 9, s = m & 511;
    *(float4*)(outp + ((size_t)(b * kH + h) * kS + s) * kDK + tx * 4) =
        make_float4(acc[i][0], acc[i][1], acc[i][2], acc[i][3]);
  }
}

// ---------------- K2: flash-style attention, 64 q-rows per block ------------
__global__ __launch_bounds__(256) void k_attn(
    const float* __restrict__ Q, const float* __restrict__ K,
    const float* __restrict__ V, float* __restrict__ oa)
{
  __shared__ float Qt[64][68];
  __shared__ float Kt[64][68];
  __shared__ float Vl[64][68];
  __shared__ float Pl[64][68];
  const int qt = blockIdx.x, h = blockIdx.y, b = blockIdx.z;
  const int tid = threadIdx.x;
  const int tx = tid & 15, ty = tid >> 4;
  const int r0 = ty * 4, c0 = tx * 4;
  const size_t base = (size_t)(b * kH + h) * kS * kDK;

  {
    const int row = tid >> 2, cc = (tid & 3) * 4;
    const float* src = Q + base + (size_t)(qt * 64 + row) * kDK;
    #pragma unroll
    for (int q = 0; q < 4; ++q) {
      const int c = cc + q * 16;
      const float4 v = *(const float4*)(src + c);
      Qt[c + 0][row] = v.x; Qt[c + 1][row] = v.y; Qt[c + 2][row] = v.z; Qt[c + 3][row] = v.w;
    }
  }
  float m_r[4], l_r[4], O[4][4];
  #pragma unroll
  for (int i = 0; i < 4; ++i) {
    m_r[i] = -__builtin_huge_valf(); l_r[i] = 0.f;
    #pragma unroll
    for (int j = 0; j < 4; ++j) O[i][j] = 0.f;
  }
  for (int kt = 0; kt < 8; ++kt) {
    __syncthreads();
    {
      const int row = tid >> 2, cc = (tid & 3) * 4;
      const float* srck = K + base + (size_t)(kt * 64 + row) * kDK;
      const float* srcv = V + base + (size_t)(kt * 64 + row) * kDK;
      #pragma unroll
      for (int q = 0; q < 4; ++q) {
        const int c = cc + q * 16;
        const float4 v = *(const float4*)(srck + c);
        Kt[c + 0][row] = v.x; Kt[c + 1][row] = v.y; Kt[c + 2][row] = v.z; Kt[c + 3][row] = v.w;
        *(float4*)&Vl[row][c] = *(const float4*)(srcv + c);
      }
    }
    __syncthreads();
    float sc[4][4] = {};
    for (int k = 0; k < 64; ++k) {
      const float4 a = *(const float4*)&Qt[k][r0];
      const float4 bb = *(const float4*)&Kt[k][c0];
      const float av[4] = {a.x, a.y, a.z, a.w};
      const float bv[4] = {bb.x, bb.y, bb.z, bb.w};
      #pragma unroll
      for (int i = 0; i < 4; ++i)
        #pragma unroll
        for (int j = 0; j < 4; ++j) sc[i][j] += av[i] * bv[j];
    }
    #pragma unroll
    for (int i = 0; i < 4; ++i) {
      #pragma unroll
      for (int j = 0; j < 4; ++j) sc[i][j] *= 0.125f;   // /sqrt(64), exact
      float tm = fmaxf(fmaxf(sc[i][0], sc[i][1]), fmaxf(sc[i][2], sc[i][3]));
      #pragma unroll
      for (int m = 1; m < 16; m <<= 1) tm = fmaxf(tm, __shfl_xor(tm, m, 16));
      const float mn = fmaxf(m_r[i], tm);
      const float corr = expf(m_r[i] - mn);              // first tile: exp(-inf)=0
      float ts = 0.f;
      #pragma unroll
      for (int j = 0; j < 4; ++j) { sc[i][j] = expf(sc[i][j] - mn); ts += sc[i][j]; }
      #pragma unroll
      for (int m = 1; m < 16; m <<= 1) ts += __shfl_xor(ts, m, 16);
      l_r[i] = l_r[i] * corr + ts;
      m_r[i] = mn;
      #pragma unroll
      for (int j = 0; j < 4; ++j) O[i][j] *= corr;
    }
    #pragma unroll
    for (int j = 0; j < 4; ++j)
      *(float4*)&Pl[c0 + j][r0] = make_float4(sc[0][j], sc[1][j], sc[2][j], sc[3][j]);
    __syncthreads();
    for (int c = 0; c < 64; ++c) {
      const float4 a = *(const float4*)&Pl[c][r0];
      const float4 bb = *(const float4*)&Vl[c][c0];
      const float av[4] = {a.x, a.y, a.z, a.w};
      const float bv[4] = {bb.x, bb.y, bb.z, bb.w};
      #pragma unroll
      for (int i = 0; i < 4; ++i)
        #pragma unroll
        for (int j = 0; j < 4; ++j) O[i][j] += av[i] * bv[j];
    }
  }
  #pragma unroll
  for (int i = 0; i < 4; ++i) {
    const int s = qt * 64 + r0 + i;
    *(float4*)(oa + ((size_t)(b * kS + s) * kH + h) * 64 + c0) =
        make_float4(O[i][0] / l_r[i], O[i][1] / l_r[i], O[i][2] / l_r[i], O[i][3] / l_r[i]);
  }
}

// ------- K3: fused proj + residual + LayerNorm(ddof=1) + lin1/tanh + lin2 ---
__global__ __launch_bounds__(256) void k_head(
    const float* __restrict__ X, const float* __restrict__ oa,
    const float* __restrict__ pw, const float* __restrict__ pb,
    const float* __restrict__ lng, const float* __restrict__ lnb,
    const float* __restrict__ w1, const float* __restrict__ b1,
    const float* __restrict__ w2, const float* __restrict__ b2,
    float* __restrict__ logits)
{
  __shared__ float xl[16][772];
  __shared__ float oal[16][196];
  __shared__ float hl[16][388];
  const int tid = threadIdx.x;
  const int row0 = blockIdx.x * 16;
  {
    const int r = tid >> 4, seg = tid & 15;
    const float* src = X + (size_t)(row0 + r) * kD;
    #pragma unroll
    for (int q = 0; q < 12; ++q) {
      const int c4 = seg + q * 16;
      *(float4*)&xl[r][c4 * 4] = *(const float4*)(src + c4 * 4);
    }
    const float* srco = oa + (size_t)(row0 + r) * 192;
    #pragma unroll
    for (int q = 0; q < 3; ++q) {
      const int c4 = seg + q * 16;
      *(float4*)&oal[r][c4 * 4] = *(const float4*)(srco + c4 * 4);
    }
  }
  __syncthreads();
  #pragma unroll
  for (int pass = 0; pass < 3; ++pass) {
    const int cc = pass * 256 + tid;
    float acc[16] = {};
    for (int k = 0; k < 192; ++k) {
      const float w = pw[(size_t)k * kD + cc];
      #pragma unroll
      for (int r = 0; r < 16; ++r) acc[r] += oal[r][k] * w;
    }
    const float pbv = pb[cc];
    #pragma unroll
    for (int r = 0; r < 16; ++r) xl[r][cc] = acc[r] + pbv + xl[r][cc];
  }
  __syncthreads();
  {
    const int rr = tid >> 4, g = tid & 15;
    float sm = 0.f;
    #pragma unroll
    for (int q = 0; q < 48; ++q) sm += xl[rr][g + q * 16];
    #pragma unroll
    for (int m = 1; m < 16; m <<= 1) sm += __shfl_xor(sm, m, 16);
    const float mu = sm / 768.0f;
    float s2 = 0.f;
    #pragma unroll
    for (int q = 0; q < 48; ++q) { const float d = xl[rr][g + q * 16] - mu; s2 += d * d; }
    #pragma unroll
    for (int m = 1; m < 16; m <<= 1) s2 += __shfl_xor(s2, m, 16);
    const float den = sqrtf(s2 / 767.0f) + 1e-3f;   // std(ddof=1) + eps
    #pragma unroll
    for (int q = 0; q < 48; ++q) {
      const int c = g + q * 16;
      xl[rr][c] = (xl[rr][c] - mu) / den * lng[c] + lnb[c];
    }
  }
  __syncthreads();
  #pragma unroll
  for (int pass = 0; pass < 2; ++pass) {
    const int cc = pass * 256 + tid;
    if (cc < 384) {
      float acc[16] = {};
      for (int k = 0; k < 768; ++k) {
        const float w = w1[(size_t)k * 384 + cc];
        #pragma unroll
        for (int r = 0; r < 16; ++r) acc[r] += xl[r][k] * w;
      }
      const float bv = b1[cc];
      #pragma unroll
      for (int r = 0; r < 16; ++r) hl[r][cc] = tanhf(acc[r] + bv);
    }
  }
  __syncthreads();
  for (int idx = tid; idx < 16 * kTAG; idx += 256) {
    const int r = idx / kTAG, j = idx - r * kTAG;
    float acc = 0.f;
    for (int k = 0; k < 384; ++k) acc += hl[r][k] * w2[(size_t)k * kTAG + j];
    logits[(size_t)(row0 + r) * kTAG + j] = acc + b2[j];
  }
}

// ---------------- K4: Viterbi beam DP — exact 2-phase pruned top-8 ----------
__device__ __forceinline__ unsigned long long vk_key(float v, unsigned lowbits) {
  unsigned u = __float_as_uint(v);
  u = (u & 0x80000000u) ? ~u : (u | 0x80000000u);
  return ((unsigned long long)u << 32) | lowbits;
}
__device__ __forceinline__ float vk_val(unsigned long long k) {
  unsigned u = (unsigned)(k >> 32);
  u = (u & 0x80000000u) ? (u & 0x7fffffffu) : ~u;
  return __uint_as_float(u);
}
__device__ __forceinline__ int vk_idx(unsigned long long k) {
  return (int)(~(unsigned)k);
}
__device__ __forceinline__ unsigned long long u64pack(unsigned lo, unsigned hi) {
  return ((unsigned long long)hi << 32) | lo;
}
// max over each aligned 8-lane group, via VALU-latency DPP (xor1, xor2, lane^7)
__device__ __forceinline__ unsigned long long dpp8_max(unsigned long long v) {
  unsigned lo = (unsigned)v, hi = (unsigned)(v >> 32);
  {
    unsigned a = (unsigned)__builtin_amdgcn_update_dpp((int)lo, (int)lo, 0xB1, 0xF, 0xF, false);
    unsigned c = (unsigned)__builtin_amdgcn_update_dpp((int)hi, (int)hi, 0xB1, 0xF, 0xF, false);
    if (u64pack(a, c) > u64pack(lo, hi)) { lo = a; hi = c; }
  }
  {
    unsigned a = (unsigned)__builtin_amdgcn_update_dpp((int)lo, (int)lo, 0x4E, 0xF, 0xF, false);
    unsigned c = (unsigned)__builtin_amdgcn_update_dpp((int)hi, (int)hi, 0x4E, 0xF, 0xF, false);
    if (u64pack(a, c) > u64pack(lo, hi)) { lo = a; hi = c; }
  }
  {
    unsigned a = (unsigned)__builtin_amdgcn_update_dpp((int)lo, (int)lo, 0x141, 0xF, 0xF, false);
    unsigned c = (unsigned)__builtin_amdgcn_update_dpp((int)hi, (int)hi, 0x141, 0xF, 0xF, false);
    if (u64pack(a, c) > u64pack(lo, hi)) { lo = a; hi = c; }
  }
  return u64pack(lo, hi);
}
__device__ __forceinline__ void ce64(unsigned long long& a, unsigned long long& b) {
  const unsigned long long lo = (a < b) ? a : b;
  a = (a < b) ? b : a;
  b = lo;
}

// Exact top-8 of the 264 candidates cand[i*8+n] = (lg + trans[i][j]) + rows[i][n].
// Phase A: top-8 head lists (provably contains all top-8 contributors).
// Phase B: 8-lane merge, one full list per lane. Results broadcast to all 8 lanes.
template <bool WITHLG>
__device__ __forceinline__ void merge8(
    const float (*rows)[12], const float* trans_colj, float lg,
    const float tr[5], const int ii[5], const bool vld[5], int g,
    float vout[8], int iout[8])
{
  // ---- Phase A: heads ----
  unsigned long long a[5];
  #pragma unroll
  for (int c = 0; c < 5; ++c) {
    const float s = WITHLG ? (lg + tr[c]) : tr[c];
    a[c] = vld[c] ? vk_key(s + rows[ii[c]][0], ~(unsigned)(ii[c] * 8)) : 0ULL;
  }
  // 9-CE sorting network (desc), Knuth S(5)
  ce64(a[0], a[1]); ce64(a[3], a[4]); ce64(a[2], a[4]); ce64(a[2], a[3]);
  ce64(a[0], a[3]); ce64(a[0], a[2]); ce64(a[1], a[4]); ce64(a[1], a[3]); ce64(a[1], a[2]);
  int L = 0;
  #pragma unroll
  for (int r = 0; r < 8; ++r) {
    const unsigned long long w = dpp8_max(a[0]);
    if (g == r) L = vk_idx(w) >> 3;
    const bool pop = (a[0] == w);
    a[0] = pop ? a[1] : a[0];
    a[1] = pop ? a[2] : a[1];
    a[2] = pop ? a[3] : a[2];
    a[3] = pop ? a[4] : a[3];
    a[4] = pop ? 0ULL : a[4];
  }
  // ---- Phase B: full list per lane ----
  const float trL = trans_colj[L * kTAG];
  const float sB = WITHLG ? (lg + trL) : trL;
  const float4* prow = (const float4*)&rows[L][0];
  const float4 r0 = prow[0], r1 = prow[1];
  const unsigned nb = ~(unsigned)(L << 3);   // ~(L*8+n) == nb - n
  unsigned long long q[8];
  q[0] = vk_key(sB + r0.x, nb - 0); q[1] = vk_key(sB + r0.y, nb - 1);
  q[2] = vk_key(sB + r0.z, nb - 2); q[3] = vk_key(sB + r0.w, nb - 3);
  q[4] = vk_key(sB + r1.x, nb - 4); q[5] = vk_key(sB + r1.y, nb - 5);
  q[6] = vk_key(sB + r1.z, nb - 6); q[7] = vk_key(sB + r1.w, nb - 7);
  #pragma unroll
  for (int r = 0; r < 8; ++r) {
    const unsigned long long w = dpp8_max(q[0]);
    vout[r] = vk_val(w);
    iout[r] = (int)(~(unsigned)w);
    const bool pop = (q[0] == w);
    q[0] = pop ? q[1] : q[0]; q[1] = pop ? q[2] : q[1];
    q[2] = pop ? q[3] : q[2]; q[3] = pop ? q[4] : q[3];
    q[4] = pop ? q[5] : q[4]; q[5] = pop ? q[6] : q[5];
    q[6] = pop ? q[7] : q[6]; q[7] = pop ? 0ULL : q[7];
  }
}

__global__ __launch_bounds__(320) void k_viterbi(
    const float* __restrict__ logits, const int* __restrict__ mask,
    const float* __restrict__ trans, unsigned short* __restrict__ bps,
    int* __restrict__ lastpos_g, int* __restrict__ ptr0_g)
{
  __shared__ __align__(16) float trans_s[kTAG][kTAG];
  __shared__ __align__(16) float part[2][kTAG][12];   // rows padded to 12 floats
  __shared__ __align__(16) float lastp[kTAG][12];
  __shared__ int mask_s[kS];
  __shared__ int lastpos_s;
  const int b = blockIdx.x, tid = threadIdx.x;
  for (int idx = tid; idx < kTAG * kTAG; idx += 320)
    trans_s[idx / kTAG][idx % kTAG] = trans[idx];
  for (int idx = tid; idx < kS; idx += 320) mask_s[idx] = mask[b * kS + idx];
  if (tid < 64) {
    int sm = 0;
    #pragma unroll
    for (int q = 0; q < 8; ++q) sm += mask[b * kS + tid * 8 + q];
    #pragma unroll
    for (int m = 1; m < 64; m <<= 1) sm += __shfl_xor(sm, m, 64);
    if (tid == 0) { lastpos_s = sm - 1; lastpos_g[b] = sm - 1; }
  }
  __syncthreads();
  const bool active = (tid < kTAG * kNB);
  const int j = tid >> 3, g = tid & 7;
  float tr[5]; int ii[5]; bool vld[5];
  float lg_next = 0.f;
  if (active) {
    #pragma unroll
    for (int c = 0; c < 5; ++c) {
      const int i0 = g + 8 * c;
      vld[c] = (i0 < kTAG);
      ii[c] = vld[c] ? i0 : (kTAG - 1);
      tr[c] = trans_s[ii[c]][j];
    }
    const float lg0 = logits[(size_t)b * kS * kTAG + j];
    part[0][j][g] = (g == 0) ? (lg0 + trans_s[kSTART][j]) : kNEG;
    lg_next = logits[((size_t)b * kS + 1) * kTAG + j];
  }

  for (int t = 1; t < kS; ++t) {
    __syncthreads();
    if (active) {
      const int pr = (t - 1) & 1, pw = t & 1;
      const int mt = mask_s[t];
      const float lg = lg_next;
      if (t + 1 < kS) lg_next = logits[((size_t)b * kS + t + 1) * kTAG + j];
      float vout[8]; int iout[8];
      merge8<true>(part[pr], &trans_s[0][j], lg, tr, ii, vld, g, vout, iout);
      if (g == 0) {
        *(float4*)&part[pw][j][0] = make_float4(vout[0], vout[1], vout[2], vout[3]);
        *(float4*)&part[pw][j][4] = make_float4(vout[4], vout[5], vout[6], vout[7]);
        if (t == lastpos_s) {
          *(float4*)&lastp[j][0] = make_float4(vout[0], vout[1], vout[2], vout[3]);
          *(float4*)&lastp[j][4] = make_float4(vout[4], vout[5], vout[6], vout[7]);
        }
        const unsigned mm = mt ? 0xFFFFFFFFu : 0u;
        const unsigned w01 = ((unsigned)iout[0] & mm) | (((unsigned)iout[1] & mm) << 16);
        const unsigned w23 = ((unsigned)iout[2] & mm) | (((unsigned)iout[3] & mm) << 16);
        const unsigned w45 = ((unsigned)iout[4] & mm) | (((unsigned)iout[5] & mm) << 16);
        const unsigned w67 = ((unsigned)iout[6] & mm) | (((unsigned)iout[7] & mm) << 16);
        *(int4*)(bps + ((size_t)t * kB + b) * (kTAG * kNB) + j * kNB) =
            make_int4((int)w01, (int)w23, (int)w45, (int)w67);
      }
    }
  }
  __syncthreads();
  if (active && j == kSTOP) {     // lanes 256..263: one aligned 8-group
    float vo[8]; int io[8];
    merge8<false>(lastp, &trans_s[0][kSTOP], 0.f, tr, ii, vld, g, vo, io);
    if (g == 0) {
      *(int4*)&ptr0_g[b * kNB + 0] = make_int4(io[0], io[1], io[2], io[3]);
      *(int4*)&ptr0_g[b * kNB + 4] = make_int4(io[4], io[5], io[6], io[7]);
    }
  }
}

// ------- K5: backtrace, per-batch block with LDS-prefetched bp rows ---------
__global__ __launch_bounds__(256) void k_backtrace(
    const unsigned short* __restrict__ bps, const int* __restrict__ ptr0,
    const int* __restrict__ lastpos, const int* __restrict__ mask,
    int* __restrict__ out)
{
  __shared__ uint4 buf[2][4][33];          // 4 rows x 264 u16 per stage
  __shared__ int ptr0_s[kNB];
  __shared__ int mask_s[kS];
  const int b = blockIdx.x, tid = threadIdx.x;
  if (tid < kNB) ptr0_s[tid] = ptr0[b * kNB + tid];
  for (int i = tid; i < kS; i += 256) mask_s[i] = mask[b * kS + i];
  const int lp = lastpos[b];
  const int lr = tid / 33, lc = tid % 33;
  if (tid < 132)
    buf[0][lr][lc] = ((const uint4*)(bps + ((size_t)(kS - 1 - lr) * kB + b) * (kTAG * kNB)))[lc];
  int p = ptr0[b * kNB];
  if (tid == 0) out[b * kS + kS - 1] = p >> 3;
  __syncthreads();
  int cur = 0, tau = kS - 2;
  while (tau >= 0) {
    const int cnt = (tau >= 3) ? 4 : (tau + 1);
    const int ntau = tau - cnt;
    uint4 v; bool have = false;
    if (ntau >= 0 && tid < 132) {
      const int cnt2 = (ntau >= 3) ? 4 : (ntau + 1);
      if (lr < cnt2) {
        v = ((const uint4*)(bps + ((size_t)(ntau + 1 - lr) * kB + b) * (kTAG * kNB)))[lc];
        have = true;
      }
    }
    for (int s2 = 0; s2 < cnt; ++s2) {
      const int t2 = tau - s2;
      int np;
      if (t2 == lp) np = ptr0_s[p & 7];
      else np = ((const unsigned short*)&buf[cur][s2][0])[p];
      if (tid == 0) out[b * kS + t2] = np >> 3;
      p = mask_s[t2] ? np : (np + p);
    }
    __syncthreads();
    if (have) buf[cur ^ 1][lr][lc] = v;
    __syncthreads();
    cur ^= 1; tau = ntau;
  }
}

extern "C" void kernel_launch(void* const* d_in, const int* in_sizes, int n_in,
                              void* d_out, int out_size, void* d_ws, size_t ws_size,
                              hipStream_t stream) {
  if (ws_size < kWsNeed) return;  // fail loudly rather than corrupt memory
  const float* X   = (const float*)d_in[0];
  const int*   msk = (const int*)d_in[1];
  const float* wq  = (const float*)d_in[2];
  const float* wk  = (const float*)d_in[3];
  const float* wv  = (const float*)d_in[4];
  const float* pw  = (const float*)d_in[5];
  const float* pb  = (const float*)d_in[6];
  const float* lng = (const float*)d_in[7];
  const float* lnb = (const float*)d_in[8];
  const float* w1  = (const float*)d_in[9];
  const float* b1  = (const float*)d_in[10];
  const float* w2  = (const float*)d_in[11];
  const float* b2  = (const float*)d_in[12];
  const float* trn = (const float*)d_in[13];
  float* ws = (float*)d_ws;

  k_qkv<<<dim3(9, 256), 256, 0, stream>>>(X, wq, wk, wv, ws);
  k_attn<<<dim3(8, 3, 64), 256, 0, stream>>>(ws + kQOFF, ws + kKOFF, ws + kVOFF, ws + kOAOFF);
  k_head<<<2048, 256, 0, stream>>>(X, ws + kOAOFF, pw, pb, lng, lnb, w1, b1, w2, b2, ws);
  unsigned short* bps = (unsigned short*)((char*)d_ws + kBpsByte);
  int* lastpos_p = (int*)(ws + kKOFF);   // K buffer dead after attention
  int* ptr0_p = lastpos_p + kB;
  k_viterbi<<<kB, 320, 0, stream>>>(ws, msk, trn, bps, lastpos_p, ptr0_p);
  k_backtrace<<<kB, 256, 0, stream>>>(bps, ptr0_p, lastpos_p, msk, (int*)d_out);
}

// Round 4
// 3012.965 us; speedup vs baseline: 1.5956x; 1.1532x over previous
//
#include <hip/hip_runtime.h>
#include <stdint.h>

namespace {
constexpr int kB = 64, kS = 512, kD = 768, kH = 3, kDK = 64;
constexpr int kTAG = 33, kNB = 8, kSTART = 31, kSTOP = 32;
constexpr float kNEG = -1e30f;
constexpr size_t kHead = (size_t)kB * kH * kS * kDK;      // 6,291,456 floats per Q/K/V/OA buffer
constexpr size_t kQOFF = 0, kKOFF = kHead, kVOFF = 2 * kHead, kOAOFF = 3 * kHead;
constexpr size_t kWsNeed = 4 * kHead * sizeof(float);     // ~100.7 MB
constexpr size_t kBpsByte = (size_t)kB * kS * kTAG * 4;   // BPS (u16) byte offset inside dead Q region
}

// ---------------- K1: QKV projection, f32 SIMT GEMM (BM=128,BN=64,BK=16) ----
__global__ __launch_bounds__(256) void k_qkv(
    const float* __restrict__ X, const float* __restrict__ wq,
    const float* __restrict__ wk, const float* __restrict__ wv,
    float* __restrict__ ws)
{
  __shared__ float As[16][132];
  __shared__ float Bs[16][68];
  const int bx = blockIdx.x;            // 0..8 -> (type, head)
  const int m0 = blockIdx.y * 128;
  const int tid = threadIdx.x;
  const int tx = tid & 15, ty = tid >> 4;
  const int typ = bx / 3, h = bx % 3;
  const float* wptr = (typ == 0) ? wq : (typ == 1) ? wk : wv;
  float* outp = ws + ((typ == 0) ? kQOFF : (typ == 1) ? kKOFF : kVOFF);

  float acc[8][4] = {};
  const int rowA = tid >> 2, ka = (tid & 3) * 4;
  const int rowB = tid >> 6, cb = tid & 63;
  for (int k0 = 0; k0 < kD; k0 += 16) {
    #pragma unroll
    for (int half = 0; half < 2; ++half) {
      const int r = rowA + half * 64;
      const float4 v = *(const float4*)(X + (size_t)(m0 + r) * kD + k0 + ka);
      As[ka + 0][r] = v.x; As[ka + 1][r] = v.y; As[ka + 2][r] = v.z; As[ka + 3][r] = v.w;
    }
    #pragma unroll
    for (int q = 0; q < 4; ++q) {
      const int k = rowB + q * 4;
      Bs[k][cb] = wptr[((size_t)h * kD + k0 + k) * 64 + cb];
    }
    __syncthreads();
    #pragma unroll
    for (int kk = 0; kk < 16; ++kk) {
      const float4 a0 = *(const float4*)&As[kk][ty * 8];
      const float4 a1 = *(const float4*)&As[kk][ty * 8 + 4];
      const float4 b0 = *(const float4*)&Bs[kk][tx * 4];
      const float a[8] = {a0.x, a0.y, a0.z, a0.w, a1.x, a1.y, a1.z, a1.w};
      const float bv[4] = {b0.x, b0.y, b0.z, b0.w};
      #pragma unroll
      for (int i = 0; i < 8; ++i)
        #pragma unroll
        for (int j = 0; j < 4; ++j) acc[i][j] += a[i] * bv[j];
    }
    __syncthreads();
  }
  #pragma unroll
  for (int i = 0; i < 8; ++i) {
    const int m = m0 + ty * 8 + i;
    const int b = m >> 9, s = m & 511;
    *(float4*)(outp + ((size_t)(b * kH + h) * kS + s) * kDK + tx * 4) =
        make_float4(acc[i][0], acc[i][1], acc[i][2], acc[i][3]);
  }
}

// ---------------- K2: flash-style attention, 64 q-rows per block ------------
__global__ __launch_bounds__(256) void k_attn(
    const float* __restrict__ Q, const float* __restrict__ K,
    const float* __restrict__ V, float* __restrict__ oa)
{
  __shared__ float Qt[64][68];
  __shared__ float Kt[64][68];
  __shared__ float Vl[64][68];
  __shared__ float Pl[64][68];
  const int qt = blockIdx.x, h = blockIdx.y, b = blockIdx.z;
  const int tid = threadIdx.x;
  const int tx = tid & 15, ty = tid >> 4;
  const int r0 = ty * 4, c0 = tx * 4;
  const size_t base = (size_t)(b * kH + h) * kS * kDK;

  {
    const int row = tid >> 2, cc = (tid & 3) * 4;
    const float* src = Q + base + (size_t)(qt * 64 + row) * kDK;
    #pragma unroll
    for (int q = 0; q < 4; ++q) {
      const int c = cc + q * 16;
      const float4 v = *(const float4*)(src + c);
      Qt[c + 0][row] = v.x; Qt[c + 1][row] = v.y; Qt[c + 2][row] = v.z; Qt[c + 3][row] = v.w;
    }
  }
  float m_r[4], l_r[4], O[4][4];
  #pragma unroll
  for (int i = 0; i < 4; ++i) {
    m_r[i] = -__builtin_huge_valf(); l_r[i] = 0.f;
    #pragma unroll
    for (int j = 0; j < 4; ++j) O[i][j] = 0.f;
  }
  for (int kt = 0; kt < 8; ++kt) {
    __syncthreads();
    {
      const int row = tid >> 2, cc = (tid & 3) * 4;
      const float* srck = K + base + (size_t)(kt * 64 + row) * kDK;
      const float* srcv = V + base + (size_t)(kt * 64 + row) * kDK;
      #pragma unroll
      for (int q = 0; q < 4; ++q) {
        const int c = cc + q * 16;
        const float4 v = *(const float4*)(srck + c);
        Kt[c + 0][row] = v.x; Kt[c + 1][row] = v.y; Kt[c + 2][row] = v.z; Kt[c + 3][row] = v.w;
        *(float4*)&Vl[row][c] = *(const float4*)(srcv + c);
      }
    }
    __syncthreads();
    float sc[4][4] = {};
    for (int k = 0; k < 64; ++k) {
      const float4 a = *(const float4*)&Qt[k][r0];
      const float4 bb = *(const float4*)&Kt[k][c0];
      const float av[4] = {a.x, a.y, a.z, a.w};
      const float bv[4] = {bb.x, bb.y, bb.z, bb.w};
      #pragma unroll
      for (int i = 0; i < 4; ++i)
        #pragma unroll
        for (int j = 0; j < 4; ++j) sc[i][j] += av[i] * bv[j];
    }
    #pragma unroll
    for (int i = 0; i < 4; ++i) {
      #pragma unroll
      for (int j = 0; j < 4; ++j) sc[i][j] *= 0.125f;   // /sqrt(64), exact
      float tm = fmaxf(fmaxf(sc[i][0], sc[i][1]), fmaxf(sc[i][2], sc[i][3]));
      #pragma unroll
      for (int m = 1; m < 16; m <<= 1) tm = fmaxf(tm, __shfl_xor(tm, m, 16));
      const float mn = fmaxf(m_r[i], tm);
      const float corr = expf(m_r[i] - mn);              // first tile: exp(-inf)=0
      float ts = 0.f;
      #pragma unroll
      for (int j = 0; j < 4; ++j) { sc[i][j] = expf(sc[i][j] - mn); ts += sc[i][j]; }
      #pragma unroll
      for (int m = 1; m < 16; m <<= 1) ts += __shfl_xor(ts, m, 16);
      l_r[i] = l_r[i] * corr + ts;
      m_r[i] = mn;
      #pragma unroll
      for (int j = 0; j < 4; ++j) O[i][j] *= corr;
    }
    #pragma unroll
    for (int j = 0; j < 4; ++j)
      *(float4*)&Pl[c0 + j][r0] = make_float4(sc[0][j], sc[1][j], sc[2][j], sc[3][j]);
    __syncthreads();
    for (int c = 0; c < 64; ++c) {
      const float4 a = *(const float4*)&Pl[c][r0];
      const float4 bb = *(const float4*)&Vl[c][c0];
      const float av[4] = {a.x, a.y, a.z, a.w};
      const float bv[4] = {bb.x, bb.y, bb.z, bb.w};
      #pragma unroll
      for (int i = 0; i < 4; ++i)
        #pragma unroll
        for (int j = 0; j < 4; ++j) O[i][j] += av[i] * bv[j];
    }
  }
  #pragma unroll
  for (int i = 0; i < 4; ++i) {
    const int s = qt * 64 + r0 + i;
    *(float4*)(oa + ((size_t)(b * kS + s) * kH + h) * 64 + c0) =
        make_float4(O[i][0] / l_r[i], O[i][1] / l_r[i], O[i][2] / l_r[i], O[i][3] / l_r[i]);
  }
}

// ------- K3: fused proj + residual + LayerNorm(ddof=1) + lin1/tanh + lin2 ---
// v2: LDS 87->73 KB (oal/hl union -> 2 blocks/CU), k-unroll x4 with float4
// LDS reads (FMA:LDS 4:1). Accumulation order identical to v1 (ascending k,
// sequential chain) -> logits bit-identical.
__global__ __launch_bounds__(256) void k_head(
    const float* __restrict__ X, const float* __restrict__ oa,
    const float* __restrict__ pw, const float* __restrict__ pb,
    const float* __restrict__ lng, const float* __restrict__ lnb,
    const float* __restrict__ w1, const float* __restrict__ b1,
    const float* __restrict__ w2, const float* __restrict__ b2,
    float* __restrict__ logits)
{
  constexpr int XLP = 776;   // xl row stride (floats)
  constexpr int OALP = 200;  // oal row stride inside union
  constexpr int HLP = 392;   // hl row stride inside union
  __shared__ __align__(16) float xl[16 * XLP];
  __shared__ __align__(16) float uni[16 * HLP];   // oal (proj) then hl (lin1/2)
  const int tid = threadIdx.x;
  const int row0 = blockIdx.x * 16;
  {
    const int r = tid >> 4, seg = tid & 15;
    const float* src = X + (size_t)(row0 + r) * kD;
    #pragma unroll
    for (int q = 0; q < 12; ++q) {
      const int c4 = seg + q * 16;
      *(float4*)&xl[r * XLP + c4 * 4] = *(const float4*)(src + c4 * 4);
    }
    const float* srco = oa + (size_t)(row0 + r) * 192;
    #pragma unroll
    for (int q = 0; q < 3; ++q) {
      const int c4 = seg + q * 16;
      *(float4*)&uni[r * OALP + c4 * 4] = *(const float4*)(srco + c4 * 4);
    }
  }
  __syncthreads();
  // ---- proj: [16 x 192] @ [192 x 768] + bias + residual ----
  #pragma unroll
  for (int pass = 0; pass < 3; ++pass) {
    const int cc = pass * 256 + tid;
    float acc[16] = {};
    for (int k = 0; k < 192; k += 4) {
      float w[4];
      #pragma unroll
      for (int q = 0; q < 4; ++q) w[q] = pw[(size_t)(k + q) * kD + cc];
      #pragma unroll
      for (int r = 0; r < 16; ++r) {
        const float4 o4 = *(const float4*)&uni[r * OALP + k];
        acc[r] += o4.x * w[0];
        acc[r] += o4.y * w[1];
        acc[r] += o4.z * w[2];
        acc[r] += o4.w * w[3];
      }
    }
    const float pbv = pb[cc];
    #pragma unroll
    for (int r = 0; r < 16; ++r) xl[r * XLP + cc] = acc[r] + pbv + xl[r * XLP + cc];
  }
  __syncthreads();
  // ---- LayerNorm (ddof=1), row per 16-lane group ----
  {
    const int rr = tid >> 4, g = tid & 15;
    float sm = 0.f;
    #pragma unroll
    for (int q = 0; q < 48; ++q) sm += xl[rr * XLP + g + q * 16];
    #pragma unroll
    for (int m = 1; m < 16; m <<= 1) sm += __shfl_xor(sm, m, 16);
    const float mu = sm / 768.0f;
    float s2 = 0.f;
    #pragma unroll
    for (int q = 0; q < 48; ++q) { const float d = xl[rr * XLP + g + q * 16] - mu; s2 += d * d; }
    #pragma unroll
    for (int m = 1; m < 16; m <<= 1) s2 += __shfl_xor(s2, m, 16);
    const float den = sqrtf(s2 / 767.0f) + 1e-3f;   // std(ddof=1) + eps
    #pragma unroll
    for (int q = 0; q < 48; ++q) {
      const int c = g + q * 16;
      xl[rr * XLP + c] = (xl[rr * XLP + c] - mu) / den * lng[c] + lnb[c];
    }
  }
  __syncthreads();
  // ---- lin1: [16 x 768] @ [768 x 384], tanh ----
  #pragma unroll
  for (int pass = 0; pass < 2; ++pass) {
    const int cc = pass * 256 + tid;
    if (cc < 384) {
      float acc[16] = {};
      for (int k = 0; k < 768; k += 4) {
        float w[4];
        #pragma unroll
        for (int q = 0; q < 4; ++q) w[q] = w1[(size_t)(k + q) * 384 + cc];
        #pragma unroll
        for (int r = 0; r < 16; ++r) {
          const float4 x4 = *(const float4*)&xl[r * XLP + k];
          acc[r] += x4.x * w[0];
          acc[r] += x4.y * w[1];
          acc[r] += x4.z * w[2];
          acc[r] += x4.w * w[3];
        }
      }
      const float bv = b1[cc];
      #pragma unroll
      for (int r = 0; r < 16; ++r) uni[r * HLP + cc] = tanhf(acc[r] + bv);
    }
  }
  __syncthreads();
  // ---- lin2: [16 x 384] @ [384 x 33] ----
  for (int idx = tid; idx < 16 * kTAG; idx += 256) {
    const int r = idx / kTAG, j = idx - r * kTAG;
    float acc = 0.f;
    for (int k = 0; k < 384; k += 4) {
      const float4 h4 = *(const float4*)&uni[r * HLP + k];
      acc += h4.x * w2[(size_t)(k + 0) * kTAG + j];
      acc += h4.y * w2[(size_t)(k + 1) * kTAG + j];
      acc += h4.z * w2[(size_t)(k + 2) * kTAG + j];
      acc += h4.w * w2[(size_t)(k + 3) * kTAG + j];
    }
    logits[(size_t)(row0 + r) * kTAG + j] = acc + b2[j];
  }
}

// ---------------- K4: Viterbi beam DP — exact 2-phase pruned top-8 ----------
__device__ __forceinline__ unsigned long long vk_key(float v, unsigned lowbits) {
  unsigned u = __float_as_uint(v);
  u = (u & 0x80000000u) ? ~u : (u | 0x80000000u);
  return ((unsigned long long)u << 32) | lowbits;
}
__device__ __forceinline__ float vk_val(unsigned long long k) {
  unsigned u = (unsigned)(k >> 32);
  u = (u & 0x80000000u) ? (u & 0x7fffffffu) : ~u;
  return __uint_as_float(u);
}
__device__ __forceinline__ int vk_idx(unsigned long long k) {
  return (int)(~(unsigned)k);
}
__device__ __forceinline__ unsigned long long u64pack(unsigned lo, unsigned hi) {
  return ((unsigned long long)hi << 32) | lo;
}
// max over each aligned 8-lane group, via VALU-latency DPP (xor1, xor2, lane^7)
__device__ __forceinline__ unsigned long long dpp8_max(unsigned long long v) {
  unsigned lo = (unsigned)v, hi = (unsigned)(v >> 32);
  {
    unsigned a = (unsigned)__builtin_amdgcn_update_dpp((int)lo, (int)lo, 0xB1, 0xF, 0xF, false);
    unsigned c = (unsigned)__builtin_amdgcn_update_dpp((int)hi, (int)hi, 0xB1, 0xF, 0xF, false);
    if (u64pack(a, c) > u64pack(lo, hi)) { lo = a; hi = c; }
  }
  {
    unsigned a = (unsigned)__builtin_amdgcn_update_dpp((int)lo, (int)lo, 0x4E, 0xF, 0xF, false);
    unsigned c = (unsigned)__builtin_amdgcn_update_dpp((int)hi, (int)hi, 0x4E, 0xF, 0xF, false);
    if (u64pack(a, c) > u64pack(lo, hi)) { lo = a; hi = c; }
  }
  {
    unsigned a = (unsigned)__builtin_amdgcn_update_dpp((int)lo, (int)lo, 0x141, 0xF, 0xF, false);
    unsigned c = (unsigned)__builtin_amdgcn_update_dpp((int)hi, (int)hi, 0x141, 0xF, 0xF, false);
    if (u64pack(a, c) > u64pack(lo, hi)) { lo = a; hi = c; }
  }
  return u64pack(lo, hi);
}
__device__ __forceinline__ void ce64(unsigned long long& a, unsigned long long& b) {
  const unsigned long long lo = (a < b) ? a : b;
  a = (a < b) ? b : a;
  b = lo;
}

// Exact top-8 of the 264 candidates cand[i*8+n] = (lg + trans[i][j]) + rows[i][n].
// Phase A: top-8 head lists (provably contains all top-8 contributors).
// Phase B: 8-lane merge, one full list per lane. Results broadcast to all 8 lanes.
template <bool WITHLG>
__device__ __forceinline__ void merge8(
    const float (*rows)[12], const float* trans_colj, float lg,
    const float tr[5], const int ii[5], const bool vld[5], int g,
    float vout[8], int iout[8])
{
  // ---- Phase A: heads ----
  unsigned long long a[5];
  #pragma unroll
  for (int c = 0; c < 5; ++c) {
    const float s = WITHLG ? (lg + tr[c]) : tr[c];
    a[c] = vld[c] ? vk_key(s + rows[ii[c]][0], ~(unsigned)(ii[c] * 8)) : 0ULL;
  }
  // 9-CE sorting network (desc), Knuth S(5)
  ce64(a[0], a[1]); ce64(a[3], a[4]); ce64(a[2], a[4]); ce64(a[2], a[3]);
  ce64(a[0], a[3]); ce64(a[0], a[2]); ce64(a[1], a[4]); ce64(a[1], a[3]); ce64(a[1], a[2]);
  int L = 0;
  #pragma unroll
  for (int r = 0; r < 8; ++r) {
    const unsigned long long w = dpp8_max(a[0]);
    if (g == r) L = vk_idx(w) >> 3;
    const bool pop = (a[0] == w);
    a[0] = pop ? a[1] : a[0];
    a[1] = pop ? a[2] : a[1];
    a[2] = pop ? a[3] : a[2];
    a[3] = pop ? a[4] : a[3];
    a[4] = pop ? 0ULL : a[4];
  }
  // ---- Phase B: full list per lane ----
  const float trL = trans_colj[L * kTAG];
  const float sB = WITHLG ? (lg + trL) : trL;
  const float4* prow = (const float4*)&rows[L][0];
  const float4 r0 = prow[0], r1 = prow[1];
  const unsigned nb = ~(unsigned)(L << 3);   // ~(L*8+n) == nb - n
  unsigned long long q[8];
  q[0] = vk_key(sB + r0.x, nb - 0); q[1] = vk_key(sB + r0.y, nb - 1);
  q[2] = vk_key(sB + r0.z, nb - 2); q[3] = vk_key(sB + r0.w, nb - 3);
  q[4] = vk_key(sB + r1.x, nb - 4); q[5] = vk_key(sB + r1.y, nb - 5);
  q[6] = vk_key(sB + r1.z, nb - 6); q[7] = vk_key(sB + r1.w, nb - 7);
  #pragma unroll
  for (int r = 0; r < 8; ++r) {
    const unsigned long long w = dpp8_max(q[0]);
    vout[r] = vk_val(w);
    iout[r] = (int)(~(unsigned)w);
    const bool pop = (q[0] == w);
    q[0] = pop ? q[1] : q[0]; q[1] = pop ? q[2] : q[1];
    q[2] = pop ? q[3] : q[2]; q[3] = pop ? q[4] : q[3];
    q[4] = pop ? q[5] : q[4]; q[5] = pop ? q[6] : q[5];
    q[6] = pop ? q[7] : q[6]; q[7] = pop ? 0ULL : q[7];
  }
}

__global__ __launch_bounds__(320) void k_viterbi(
    const float* __restrict__ logits, const int* __restrict__ mask,
    const float* __restrict__ trans, unsigned short* __restrict__ bps,
    int* __restrict__ lastpos_g, int* __restrict__ ptr0_g)
{
  __shared__ __align__(16) float trans_s[kTAG][kTAG];
  __shared__ __align__(16) float part[2][kTAG][12];   // rows padded to 12 floats
  __shared__ __align__(16) float lastp[kTAG][12];
  __shared__ int mask_s[kS];
  __shared__ int lastpos_s;
  const int b = blockIdx.x, tid = threadIdx.x;
  for (int idx = tid; idx < kTAG * kTAG; idx += 320)
    trans_s[idx / kTAG][idx % kTAG] = trans[idx];
  for (int idx = tid; idx < kS; idx += 320) mask_s[idx] = mask[b * kS + idx];
  if (tid < 64) {
    int sm = 0;
    #pragma unroll
    for (int q = 0; q < 8; ++q) sm += mask[b * kS + tid * 8 + q];
    #pragma unroll
    for (int m = 1; m < 64; m <<= 1) sm += __shfl_xor(sm, m, 64);
    if (tid == 0) { lastpos_s = sm - 1; lastpos_g[b] = sm - 1; }
  }
  __syncthreads();
  const bool active = (tid < kTAG * kNB);
  const int j = tid >> 3, g = tid & 7;
  float tr[5]; int ii[5]; bool vld[5];
  float lg_next = 0.f;
  if (active) {
    #pragma unroll
    for (int c = 0; c < 5; ++c) {
      const int i0 = g + 8 * c;
      vld[c] = (i0 < kTAG);
      ii[c] = vld[c] ? i0 : (kTAG - 1);
      tr[c] = trans_s[ii[c]][j];
    }
    const float lg0 = logits[(size_t)b * kS * kTAG + j];
    part[0][j][g] = (g == 0) ? (lg0 + trans_s[kSTART][j]) : kNEG;
    lg_next = logits[((size_t)b * kS + 1) * kTAG + j];
  }

  for (int t = 1; t < kS; ++t) {
    __syncthreads();
    if (active) {
      const int pr = (t - 1) & 1, pw = t & 1;
      const int mt = mask_s[t];
      const float lg = lg_next;
      if (t + 1 < kS) lg_next = logits[((size_t)b * kS + t + 1) * kTAG + j];
      float vout[8]; int iout[8];
      merge8<true>(part[pr], &trans_s[0][j], lg, tr, ii, vld, g, vout, iout);
      if (g == 0) {
        *(float4*)&part[pw][j][0] = make_float4(vout[0], vout[1], vout[2], vout[3]);
        *(float4*)&part[pw][j][4] = make_float4(vout[4], vout[5], vout[6], vout[7]);
        if (t == lastpos_s) {
          *(float4*)&lastp[j][0] = make_float4(vout[0], vout[1], vout[2], vout[3]);
          *(float4*)&lastp[j][4] = make_float4(vout[4], vout[5], vout[6], vout[7]);
        }
        const unsigned mm = mt ? 0xFFFFFFFFu : 0u;
        const unsigned w01 = ((unsigned)iout[0] & mm) | (((unsigned)iout[1] & mm) << 16);
        const unsigned w23 = ((unsigned)iout[2] & mm) | (((unsigned)iout[3] & mm) << 16);
        const unsigned w45 = ((unsigned)iout[4] & mm) | (((unsigned)iout[5] & mm) << 16);
        const unsigned w67 = ((unsigned)iout[6] & mm) | (((unsigned)iout[7] & mm) << 16);
        *(int4*)(bps + ((size_t)t * kB + b) * (kTAG * kNB) + j * kNB) =
            make_int4((int)w01, (int)w23, (int)w45, (int)w67);
      }
    }
  }
  __syncthreads();
  if (active && j == kSTOP) {     // lanes 256..263: one aligned 8-group
    float vo[8]; int io[8];
    merge8<false>(lastp, &trans_s[0][kSTOP], 0.f, tr, ii, vld, g, vo, io);
    if (g == 0) {
      *(int4*)&ptr0_g[b * kNB + 0] = make_int4(io[0], io[1], io[2], io[3]);
      *(int4*)&ptr0_g[b * kNB + 4] = make_int4(io[4], io[5], io[6], io[7]);
    }
  }
}

// ------- K5: backtrace, per-batch block with LDS-prefetched bp rows ---------
__global__ __launch_bounds__(256) void k_backtrace(
    const unsigned short* __restrict__ bps, const int* __restrict__ ptr0,
    const int* __restrict__ lastpos, const int* __restrict__ mask,
    int* __restrict__ out)
{
  __shared__ uint4 buf[2][4][33];          // 4 rows x 264 u16 per stage
  __shared__ int ptr0_s[kNB];
  __shared__ int mask_s[kS];
  const int b = blockIdx.x, tid = threadIdx.x;
  if (tid < kNB) ptr0_s[tid] = ptr0[b * kNB + tid];
  for (int i = tid; i < kS; i += 256) mask_s[i] = mask[b * kS + i];
  const int lp = lastpos[b];
  const int lr = tid / 33, lc = tid % 33;
  if (tid < 132)
    buf[0][lr][lc] = ((const uint4*)(bps + ((size_t)(kS - 1 - lr) * kB + b) * (kTAG * kNB)))[lc];
  int p = ptr0[b * kNB];
  if (tid == 0) out[b * kS + kS - 1] = p >> 3;
  __syncthreads();
  int cur = 0, tau = kS - 2;
  while (tau >= 0) {
    const int cnt = (tau >= 3) ? 4 : (tau + 1);
    const int ntau = tau - cnt;
    uint4 v; bool have = false;
    if (ntau >= 0 && tid < 132) {
      const int cnt2 = (ntau >= 3) ? 4 : (ntau + 1);
      if (lr < cnt2) {
        v = ((const uint4*)(bps + ((size_t)(ntau + 1 - lr) * kB + b) * (kTAG * kNB)))[lc];
        have = true;
      }
    }
    for (int s2 = 0; s2 < cnt; ++s2) {
      const int t2 = tau - s2;
      int np;
      if (t2 == lp) np = ptr0_s[p & 7];
      else np = ((const unsigned short*)&buf[cur][s2][0])[p];
      if (tid == 0) out[b * kS + t2] = np >> 3;
      p = mask_s[t2] ? np : (np + p);
    }
    __syncthreads();
    if (have) buf[cur ^ 1][lr][lc] = v;
    __syncthreads();
    cur ^= 1; tau = ntau;
  }
}

extern "C" void kernel_launch(void* const* d_in, const int* in_sizes, int n_in,
                              void* d_out, int out_size, void* d_ws, size_t ws_size,
                              hipStream_t stream) {
  if (ws_size < kWsNeed) return;  // fail loudly rather than corrupt memory
  const float* X   = (const float*)d_in[0];
  const int*   msk = (const int*)d_in[1];
  const float* wq  = (const float*)d_in[2];
  const float* wk  = (const float*)d_in[3];
  const float* wv  = (const float*)d_in[4];
  const float* pw  = (const float*)d_in[5];
  const float* pb  = (const float*)d_in[6];
  const float* lng = (const float*)d_in[7];
  const float* lnb = (const float*)d_in[8];
  const float* w1  = (const float*)d_in[9];
  const float* b1  = (const float*)d_in[10];
  const float* w2  = (const float*)d_in[11];
  const float* b2  = (const float*)d_in[12];
  const float* trn = (const float*)d_in[13];
  float* ws = (float*)d_ws;

  k_qkv<<<dim3(9, 256), 256, 0, stream>>>(X, wq, wk, wv, ws);
  k_attn<<<dim3(8, 3, 64), 256, 0, stream>>>(ws + kQOFF, ws + kKOFF, ws + kVOFF, ws + kOAOFF);
  k_head<<<2048, 256, 0, stream>>>(X, ws + kOAOFF, pw, pb, lng, lnb, w1, b1, w2, b2, ws);
  unsigned short* bps = (unsigned short*)((char*)d_ws + kBpsByte);
  int* lastpos_p = (int*)(ws + kKOFF);   // K buffer dead after attention
  int* ptr0_p = lastpos_p + kB;
  k_viterbi<<<kB, 320, 0, stream>>>(ws, msk, trn, bps, lastpos_p, ptr0_p);
  k_backtrace<<<kB, 256, 0, stream>>>(bps, ptr0_p, lastpos_p, msk, (int*)d_out);
}